// Round 1
// baseline (204.989 us; speedup 1.0000x reference)
//
#include <hip/hip_runtime.h>

// Problem constants (from reference)
#define LATENT 128
#define DQK    32
#define BB     4
#define NN     16384
#define KK     64
#define NK     (NN * KK)          // 2^20 edges per batch
#define TOTAL_EDGES (BB * NK)     // 4,194,304
#define TOTAL_NODES (BB * NN)     // 65,536

// ---------------------------------------------------------------------------
// Kernel 1: ks = features @ Wk^T + bk ; qs = features @ Wq^T + bq
// Block = 256 threads = 8 nodes x 32 d-lanes.
// ---------------------------------------------------------------------------
__global__ __launch_bounds__(256) void proj_kernel(
    const float* __restrict__ features,  // [B*N, 128]
    const float* __restrict__ Wk,        // [32, 128]
    const float* __restrict__ bk,        // [32]
    const float* __restrict__ Wq,        // [32, 128]
    const float* __restrict__ bq,        // [32]
    float* __restrict__ ks,              // [B*N, 32]
    float* __restrict__ qs)              // [B*N, 32]
{
    __shared__ float wkT[LATENT][DQK + 1];   // +1 pad: conflict-free
    __shared__ float wqT[LATENT][DQK + 1];
    __shared__ float sbk[DQK], sbq[DQK];
    __shared__ float feats[8][LATENT];

    const int t = threadIdx.x;

    // Load W (32x128 row-major) transposed into LDS: 4096 elems / 256 thr = 16 iters
    #pragma unroll
    for (int j = 0; j < (DQK * LATENT) / 256; ++j) {
        int idx = t + j * 256;
        int d = idx >> 7;        // / 128
        int l = idx & 127;
        wkT[l][d] = Wk[idx];
        wqT[l][d] = Wq[idx];
    }
    if (t < DQK) { sbk[t] = bk[t]; sbq[t] = bq[t]; }

    // Load 8 feature rows (1024 floats = 256 float4), fully coalesced
    const int node0 = blockIdx.x * 8;
    const float4* frow = (const float4*)(features + (size_t)node0 * LATENT);
    float4* fl = (float4*)(&feats[0][0]);
    fl[t] = frow[t];

    __syncthreads();

    const int nl = t >> 5;    // node within block
    const int d  = t & 31;    // output dim
    float ak = 0.f, aq = 0.f;
    #pragma unroll 16
    for (int l = 0; l < LATENT; ++l) {
        float f = feats[nl][l];          // broadcast within lane-groups
        ak = fmaf(f, wkT[l][d], ak);     // banks 0..31, conflict-free
        aq = fmaf(f, wqT[l][d], aq);
    }

    const int node = node0 + nl;
    ks[(size_t)node * DQK + d] = ak + sbk[d];   // coalesced
    qs[(size_t)node * DQK + d] = aq + sbq[d];
}

// ---------------------------------------------------------------------------
// Kernel 2: per-edge gather + 32-dim dot product
// One thread per edge. Gathered rows are 128 B contiguous (8x float4).
// ks/qs are 2 MB per batch -> L2-resident; HBM traffic is indices + output.
// ---------------------------------------------------------------------------
__global__ __launch_bounds__(256) void edge_kernel(
    const int* __restrict__ xidx,   // indices[1] flat, [B*N*K]
    const int* __restrict__ yidx,   // indices[2] flat
    const float* __restrict__ ks,   // [B*N, 32]
    const float* __restrict__ qs,
    float* __restrict__ out)        // [B*N*K]
{
    const int e = blockIdx.x * 256 + threadIdx.x;
    const int b = e >> 20;          // N*K = 2^20
    const int x = xidx[e];
    const int y = yidx[e];

    const float4* kp = (const float4*)(ks + ((size_t)(b * NN + x)) * DQK);
    const float4* qp = (const float4*)(qs + ((size_t)(b * NN + y)) * DQK);

    float acc = 0.f;
    #pragma unroll
    for (int j = 0; j < 8; ++j) {
        float4 kv = kp[j];
        float4 qv = qp[j];
        acc += kv.x * qv.x + kv.y * qv.y + kv.z * qv.z + kv.w * qv.w;
    }
    out[e] = acc * 0.17677669529663687f;   // 32^-0.5
}

// ---------------------------------------------------------------------------
extern "C" void kernel_launch(void* const* d_in, const int* in_sizes, int n_in,
                              void* d_out, int out_size, void* d_ws, size_t ws_size,
                              hipStream_t stream) {
    // Input order: indices, img, features, Wk, bk, Wq, bq
    const int*   indices  = (const int*)d_in[0];    // [3, B, N, K] int32
    const float* features = (const float*)d_in[2];  // [B, N, 128]
    const float* Wk       = (const float*)d_in[3];
    const float* bk       = (const float*)d_in[4];
    const float* Wq       = (const float*)d_in[5];
    const float* bq       = (const float*)d_in[6];
    float* out = (float*)d_out;

    // Workspace: ks then qs, each [B*N, 32] f32 = 8.4 MB
    float* ks = (float*)d_ws;
    float* qs = ks + (size_t)TOTAL_NODES * DQK;

    const int* xidx = indices + (size_t)1 * TOTAL_EDGES;  // row 1 -> keys
    const int* yidx = indices + (size_t)2 * TOTAL_EDGES;  // row 2 -> queries

    proj_kernel<<<TOTAL_NODES / 8, 256, 0, stream>>>(features, Wk, bk, Wq, bq, ks, qs);
    edge_kernel<<<TOTAL_EDGES / 256, 256, 0, stream>>>(xidx, yidx, ks, qs, out);
}

// Round 2
// 174.879 us; speedup vs baseline: 1.1722x; 1.1722x over previous
//
#include <hip/hip_runtime.h>
#include <hip/hip_fp16.h>

#define LATENT 128
#define DQK    32
#define BB     4
#define NN     16384
#define KK     64
#define TOTAL_EDGES (BB * NN * KK)   // 4,194,304 (NK per batch = 2^20)
#define TOTAL_NODES (BB * NN)        // 65,536

// ---------------------------------------------------------------------------
// Kernel 1: ks/qs = features @ W^T + b, output f16.
// One thread per node. Feature row (128 f32) held in 32 float4 registers.
// Weight rows are read at wave-uniform addresses -> scalar (s_load) path,
// FMA operands come from SGPRs; no LDS at all.
// Grid = 256 blocks x 256 threads = 65536 threads = 1024 waves (1/SIMD).
// ---------------------------------------------------------------------------
__global__ __launch_bounds__(256, 1) void proj_kernel(
    const float* __restrict__ features,  // [B*N, 128]
    const float* __restrict__ Wk,        // [32, 128] row-major
    const float* __restrict__ bk,        // [32]
    const float* __restrict__ Wq,        // [32, 128]
    const float* __restrict__ bq,        // [32]
    __half* __restrict__ ks,             // [B*N, 32] f16
    __half* __restrict__ qs)             // [B*N, 32] f16
{
    const int node = blockIdx.x * 256 + threadIdx.x;

    // Load full feature row into registers (lane-divergent, but rows are
    // 512 B contiguous per lane -> L1 captures the 4x line reuse).
    const float4* frow = (const float4*)features + (size_t)node * 32;
    float4 f[32];
    #pragma unroll
    for (int i = 0; i < 32; ++i) f[i] = frow[i];

    const float4* wk4 = (const float4*)Wk;
    const float4* wq4 = (const float4*)Wq;
    uint4* krow = (uint4*)ks + (size_t)node * 4;   // 32 halves = 4 uint4
    uint4* qrow = (uint4*)qs + (size_t)node * 4;

    for (int dg = 0; dg < 4; ++dg) {               // 8 output dims per iter
        const int d0 = dg * 8;
        float ak[8], aq[8];
        #pragma unroll
        for (int u = 0; u < 8; ++u) { ak[u] = bk[d0 + u]; aq[u] = bq[d0 + u]; }

        #pragma unroll
        for (int u = 0; u < 8; ++u) {
            const float4* wkr = wk4 + (size_t)(d0 + u) * 32;  // uniform addr
            const float4* wqr = wq4 + (size_t)(d0 + u) * 32;
            float sk = 0.f, sq = 0.f;
            #pragma unroll
            for (int i = 0; i < 32; ++i) {
                const float4 v = f[i];
                float4 w = wkr[i];
                sk += w.x * v.x + w.y * v.y + w.z * v.z + w.w * v.w;
                w = wqr[i];
                sq += w.x * v.x + w.y * v.y + w.z * v.z + w.w * v.w;
            }
            ak[u] += sk; aq[u] += sq;
        }

        // Pack 8 f32 -> 8 f16 -> uint4, one 16 B store per matrix.
        uint4 pk, pq;
        {
            __half2 h;
            h = __floats2half2_rn(ak[0], ak[1]); pk.x = *(unsigned int*)&h;
            h = __floats2half2_rn(ak[2], ak[3]); pk.y = *(unsigned int*)&h;
            h = __floats2half2_rn(ak[4], ak[5]); pk.z = *(unsigned int*)&h;
            h = __floats2half2_rn(ak[6], ak[7]); pk.w = *(unsigned int*)&h;
            h = __floats2half2_rn(aq[0], aq[1]); pq.x = *(unsigned int*)&h;
            h = __floats2half2_rn(aq[2], aq[3]); pq.y = *(unsigned int*)&h;
            h = __floats2half2_rn(aq[4], aq[5]); pq.z = *(unsigned int*)&h;
            h = __floats2half2_rn(aq[6], aq[7]); pq.w = *(unsigned int*)&h;
        }
        krow[dg] = pk;
        qrow[dg] = pq;
    }
}

// ---------------------------------------------------------------------------
// Kernel 2: per-edge gather + dot. 4 lanes per edge, 16 B (8 f16) per lane.
// One gather instruction covers 16 full 64 B rows (16 lines vs 64 before).
// Reduce partial dot across the 4-lane group with __shfl_xor.
// ---------------------------------------------------------------------------
__device__ __forceinline__ float dot8_h(uint4 a, uint4 b) {
    const __half2* ah = (const __half2*)&a;
    const __half2* bh = (const __half2*)&b;
    float s = 0.f;
    #pragma unroll
    for (int i = 0; i < 4; ++i) {
        const float2 af = __half22float2(ah[i]);
        const float2 bf = __half22float2(bh[i]);
        s += af.x * bf.x + af.y * bf.y;
    }
    return s;
}

__global__ __launch_bounds__(256) void edge_kernel(
    const int* __restrict__ xidx,   // indices[1] flat, [B*N*K]
    const int* __restrict__ yidx,   // indices[2] flat
    const __half* __restrict__ ks,  // [B*N, 32] f16
    const __half* __restrict__ qs,
    float* __restrict__ out)        // [B*N*K]
{
    const int t = blockIdx.x * 256 + threadIdx.x;
    const int e = t >> 2;           // edge index
    const int j = t & 3;            // 16 B chunk within the 64 B row
    const int b = e >> 20;          // N*K = 2^20 edges per batch

    const int x = xidx[e];          // 4 lanes load same value: 1 line/wave
    const int y = yidx[e];

    const uint4 kv = ((const uint4*)ks)[((size_t)((b << 14) + x)) * 4 + j];
    const uint4 qv = ((const uint4*)qs)[((size_t)((b << 14) + y)) * 4 + j];

    float acc = dot8_h(kv, qv);
    acc += __shfl_xor(acc, 1);
    acc += __shfl_xor(acc, 2);

    if (j == 0) out[e] = acc * 0.17677669529663687f;  // 32^-0.5
}

// ---------------------------------------------------------------------------
extern "C" void kernel_launch(void* const* d_in, const int* in_sizes, int n_in,
                              void* d_out, int out_size, void* d_ws, size_t ws_size,
                              hipStream_t stream) {
    // Input order: indices, img, features, Wk, bk, Wq, bq
    const int*   indices  = (const int*)d_in[0];
    const float* features = (const float*)d_in[2];
    const float* Wk       = (const float*)d_in[3];
    const float* bk       = (const float*)d_in[4];
    const float* Wq       = (const float*)d_in[5];
    const float* bq       = (const float*)d_in[6];
    float* out = (float*)d_out;

    // Workspace: ks, qs as f16 [B*N, 32] = 4 MB each
    __half* ks = (__half*)d_ws;
    __half* qs = ks + (size_t)TOTAL_NODES * DQK;

    const int* xidx = indices + (size_t)1 * TOTAL_EDGES;  // row 1 -> keys
    const int* yidx = indices + (size_t)2 * TOTAL_EDGES;  // row 2 -> queries

    proj_kernel<<<TOTAL_NODES / 256, 256, 0, stream>>>(features, Wk, bk, Wq, bq, ks, qs);
    edge_kernel<<<(TOTAL_EDGES * 4) / 256, 256, 0, stream>>>(xidx, yidx, ks, qs, out);
}

// Round 3
// 154.098 us; speedup vs baseline: 1.3303x; 1.1349x over previous
//
#include <hip/hip_runtime.h>
#include <hip/hip_fp16.h>

#define LATENT 128
#define DQK    32
#define BB     4
#define NN     16384
#define KK     64
#define TOTAL_EDGES (BB * NN * KK)   // 4,194,304
#define TOTAL_NODES (BB * NN)        // 65,536
#define NPW     32                   // nodes per wave
#define PROJ_WAVES (TOTAL_NODES / NPW)          // 2048
#define PROJ_BLOCKS (PROJ_WAVES / 4)            // 512 (256-thread blocks)

// ---------------------------------------------------------------------------
// Kernel 1: ks/qs = features @ W^T + b  (f16 output)
// Wave = 64 output channels: lanes 0..31 -> ks dims, 32..63 -> qs dims.
// Each lane keeps its W row (128 f32) in VGPRs, loaded once.
// The wave streams NPW nodes; the feature-row address is wave-uniform
// (readfirstlane) -> scalar loads broadcast to all lanes; 128 FMA/lane/node.
// 2048 waves = 8 waves/CU = 2/SIMD -> s_load latency hides under FMAs.
// ---------------------------------------------------------------------------
__global__ __launch_bounds__(256, 2) void proj_kernel(
    const float* __restrict__ features,  // [B*N, 128]
    const float* __restrict__ Wk,        // [32, 128] row-major
    const float* __restrict__ bk,        // [32]
    const float* __restrict__ Wq,        // [32, 128]
    const float* __restrict__ bq,        // [32]
    __half* __restrict__ ks,             // [B*N, 32] f16
    __half* __restrict__ qs)             // [B*N, 32] f16
{
    const int lane = threadIdx.x & 63;
    int wave = (blockIdx.x * 256 + threadIdx.x) >> 6;
    wave = __builtin_amdgcn_readfirstlane(wave);   // provably uniform

    const int d = lane & 31;
    const bool is_k = lane < 32;
    const float* wrow = (is_k ? Wk : Wq) + (size_t)d * LATENT;
    float4 w[32];
    #pragma unroll
    for (int i = 0; i < 32; ++i) w[i] = ((const float4*)wrow)[i];
    const float bias = (is_k ? bk : bq)[d];
    __half* outbase = is_k ? ks : qs;

    const int node0 = wave * NPW;
    #pragma unroll 2
    for (int n = 0; n < NPW; ++n) {
        const int node = node0 + n;
        const float* frow = features + (size_t)node * LATENT;  // uniform addr
        float acc = bias;
        #pragma unroll
        for (int i = 0; i < 32; ++i) {
            const float4 wv = w[i];
            acc = fmaf(frow[4 * i + 0], wv.x, acc);
            acc = fmaf(frow[4 * i + 1], wv.y, acc);
            acc = fmaf(frow[4 * i + 2], wv.z, acc);
            acc = fmaf(frow[4 * i + 3], wv.w, acc);
        }
        outbase[(size_t)node * DQK + d] = __float2half(acc);
    }
}

// ---------------------------------------------------------------------------
// Kernel 2: per-edge gather + dot. 4 lanes per edge, 16 B (8 f16) per lane.
// (unchanged from round 2: ~L2-transaction floor)
// ---------------------------------------------------------------------------
__device__ __forceinline__ float dot8_h(uint4 a, uint4 b) {
    const __half2* ah = (const __half2*)&a;
    const __half2* bh = (const __half2*)&b;
    float s = 0.f;
    #pragma unroll
    for (int i = 0; i < 4; ++i) {
        const float2 af = __half22float2(ah[i]);
        const float2 bf = __half22float2(bh[i]);
        s += af.x * bf.x + af.y * bf.y;
    }
    return s;
}

__global__ __launch_bounds__(256) void edge_kernel(
    const int* __restrict__ xidx,
    const int* __restrict__ yidx,
    const __half* __restrict__ ks,
    const __half* __restrict__ qs,
    float* __restrict__ out)
{
    const int t = blockIdx.x * 256 + threadIdx.x;
    const int e = t >> 2;           // edge index
    const int j = t & 3;            // 16 B chunk within the 64 B row
    const int b = e >> 20;          // N*K = 2^20 edges per batch

    const int x = xidx[e];
    const int y = yidx[e];

    const uint4 kv = ((const uint4*)ks)[((size_t)((b << 14) + x)) * 4 + j];
    const uint4 qv = ((const uint4*)qs)[((size_t)((b << 14) + y)) * 4 + j];

    float acc = dot8_h(kv, qv);
    acc += __shfl_xor(acc, 1);
    acc += __shfl_xor(acc, 2);

    if (j == 0) out[e] = acc * 0.17677669529663687f;  // 32^-0.5
}

// ---------------------------------------------------------------------------
extern "C" void kernel_launch(void* const* d_in, const int* in_sizes, int n_in,
                              void* d_out, int out_size, void* d_ws, size_t ws_size,
                              hipStream_t stream) {
    // Input order: indices, img, features, Wk, bk, Wq, bq
    const int*   indices  = (const int*)d_in[0];
    const float* features = (const float*)d_in[2];
    const float* Wk       = (const float*)d_in[3];
    const float* bk       = (const float*)d_in[4];
    const float* Wq       = (const float*)d_in[5];
    const float* bq       = (const float*)d_in[6];
    float* out = (float*)d_out;

    __half* ks = (__half*)d_ws;                       // [B*N, 32] f16
    __half* qs = ks + (size_t)TOTAL_NODES * DQK;

    const int* xidx = indices + (size_t)1 * TOTAL_EDGES;  // row 1 -> keys
    const int* yidx = indices + (size_t)2 * TOTAL_EDGES;  // row 2 -> queries

    proj_kernel<<<PROJ_BLOCKS, 256, 0, stream>>>(features, Wk, bk, Wq, bq, ks, qs);
    edge_kernel<<<(TOTAL_EDGES * 4) / 256, 256, 0, stream>>>(xidx, yidx, ks, qs, out);
}

// Round 4
// 74.124 us; speedup vs baseline: 2.7655x; 2.0789x over previous
//
#include <hip/hip_runtime.h>
#include <hip/hip_fp16.h>

#define LATENT 128
#define DQK    32
#define BB     4
#define NN     16384
#define KK     64
#define TOTAL_EDGES (BB * NN * KK)   // 4,194,304
#define TOTAL_NODES (BB * NN)        // 65,536
#define PAD    132                   // LDS row stride (floats): 16B-aligned, bank-spread

// ---------------------------------------------------------------------------
// Kernel 1: ks/qs = features @ W^T + b  (f16 out)
// LDS-tiled register-blocked GEMM: block = 64 nodes x 64 dims (32 ks + 32 qs),
// thread = 4 nodes x 4 dims micro-tile, K=128 in float4 steps.
// dims = tx + 16u -> ds_read_b128 row starts at banks (tx*4)%32: 2-way, free.
// ---------------------------------------------------------------------------
__global__ __launch_bounds__(256, 2) void proj_kernel(
    const float* __restrict__ features,  // [B*N, 128]
    const float* __restrict__ Wk,        // [32, 128]
    const float* __restrict__ bk,        // [32]
    const float* __restrict__ Wq,        // [32, 128]
    const float* __restrict__ bq,        // [32]
    __half* __restrict__ ks,             // [B*N, 32] f16
    __half* __restrict__ qs)             // [B*N, 32] f16
{
    __shared__ float sf[64 * PAD];   // feature tile
    __shared__ float sw[64 * PAD];   // rows 0..31 = Wk, 32..63 = Wq
    __shared__ float sb[64];

    const int t = threadIdx.x;
    const int node0 = blockIdx.x * 64;

    // Stage W (64 rows x 32 float4 = 2048 float4; 8 per thread, coalesced)
    #pragma unroll
    for (int j = 0; j < 8; ++j) {
        int idx = t + j * 256;
        int r = idx >> 5;            // row 0..63
        int c = idx & 31;            // float4 col
        const float4* src = (r < 32) ? (const float4*)Wk : (const float4*)Wq;
        float4 v = src[(size_t)(r & 31) * 32 + c];
        *(float4*)&sw[r * PAD + c * 4] = v;
    }
    if (t < 64) sb[t] = (t < 32) ? bk[t] : bq[t - 32];

    // Stage feature tile (64 rows x 32 float4, coalesced)
    #pragma unroll
    for (int j = 0; j < 8; ++j) {
        int idx = t + j * 256;
        int r = idx >> 5;
        int c = idx & 31;
        float4 v = ((const float4*)(features + (size_t)(node0 + r) * LATENT))[c];
        *(float4*)&sf[r * PAD + c * 4] = v;
    }
    __syncthreads();

    const int tx = t & 15;           // dim group: dims tx + 16u
    const int ty = t >> 4;           // node group: nodes 4*ty + i

    float acc[4][4];
    #pragma unroll
    for (int i = 0; i < 4; ++i)
        #pragma unroll
        for (int u = 0; u < 4; ++u) acc[i][u] = 0.f;

    #pragma unroll 4
    for (int kk = 0; kk < 32; ++kk) {
        float4 a[4], b[4];
        #pragma unroll
        for (int i = 0; i < 4; ++i)
            a[i] = *(const float4*)&sf[(ty * 4 + i) * PAD + kk * 4];
        #pragma unroll
        for (int u = 0; u < 4; ++u)
            b[u] = *(const float4*)&sw[(tx + 16 * u) * PAD + kk * 4];
        #pragma unroll
        for (int i = 0; i < 4; ++i)
            #pragma unroll
            for (int u = 0; u < 4; ++u)
                acc[i][u] += a[i].x * b[u].x + a[i].y * b[u].y
                           + a[i].z * b[u].z + a[i].w * b[u].w;
    }

    // Epilogue: add bias, write f16
    #pragma unroll
    for (int u = 0; u < 4; ++u) {
        const int d = tx + 16 * u;
        const float bias = sb[d];
        __half* base = (d < 32) ? ks : qs;
        const int dd = d & 31;
        #pragma unroll
        for (int i = 0; i < 4; ++i) {
            const int node = node0 + ty * 4 + i;
            base[(size_t)node * DQK + dd] = __float2half(acc[i][u] + bias);
        }
    }
}

// ---------------------------------------------------------------------------
// Kernel 2: per-edge gather + dot. 4 lanes per edge, 16 B (8 f16) per lane.
// ---------------------------------------------------------------------------
__device__ __forceinline__ float dot8_h(uint4 a, uint4 b) {
    const __half2* ah = (const __half2*)&a;
    const __half2* bh = (const __half2*)&b;
    float s = 0.f;
    #pragma unroll
    for (int i = 0; i < 4; ++i) {
        const float2 af = __half22float2(ah[i]);
        const float2 bf = __half22float2(bh[i]);
        s += af.x * bf.x + af.y * bf.y;
    }
    return s;
}

__global__ __launch_bounds__(256) void edge_kernel(
    const int* __restrict__ xidx,
    const int* __restrict__ yidx,
    const __half* __restrict__ ks,
    const __half* __restrict__ qs,
    float* __restrict__ out)
{
    const int t = blockIdx.x * 256 + threadIdx.x;
    const int e = t >> 2;           // edge index
    const int j = t & 3;            // 16 B chunk within the 64 B row
    const int b = e >> 20;          // N*K = 2^20 edges per batch

    const int x = xidx[e];
    const int y = yidx[e];

    const uint4 kv = ((const uint4*)ks)[((size_t)((b << 14) + x)) * 4 + j];
    const uint4 qv = ((const uint4*)qs)[((size_t)((b << 14) + y)) * 4 + j];

    float acc = dot8_h(kv, qv);
    acc += __shfl_xor(acc, 1);
    acc += __shfl_xor(acc, 2);

    if (j == 0) out[e] = acc * 0.17677669529663687f;  // 32^-0.5
}

// ---------------------------------------------------------------------------
extern "C" void kernel_launch(void* const* d_in, const int* in_sizes, int n_in,
                              void* d_out, int out_size, void* d_ws, size_t ws_size,
                              hipStream_t stream) {
    // Input order: indices, img, features, Wk, bk, Wq, bq
    const int*   indices  = (const int*)d_in[0];
    const float* features = (const float*)d_in[2];
    const float* Wk       = (const float*)d_in[3];
    const float* bk       = (const float*)d_in[4];
    const float* Wq       = (const float*)d_in[5];
    const float* bq       = (const float*)d_in[6];
    float* out = (float*)d_out;

    __half* ks = (__half*)d_ws;                       // [B*N, 32] f16
    __half* qs = ks + (size_t)TOTAL_NODES * DQK;

    const int* xidx = indices + (size_t)1 * TOTAL_EDGES;  // row 1 -> keys
    const int* yidx = indices + (size_t)2 * TOTAL_EDGES;  // row 2 -> queries

    proj_kernel<<<TOTAL_NODES / 64, 256, 0, stream>>>(features, Wk, bk, Wq, bq, ks, qs);
    edge_kernel<<<(TOTAL_EDGES * 4) / 256, 256, 0, stream>>>(xidx, yidx, ks, qs, out);
}